// Round 10
// baseline (84.387 us; speedup 1.0000x reference)
//
#include <hip/hip_runtime.h>
#include <math.h>

// PCEN, v6: wave-autonomous chunked scan — zero LDS, zero barriers.
//   wave = 4 seq4 x 16 chunks x 16 steps (span 256); chain = halo span +
//   2 produce spans (512 steps). Carry across chunks via in-wave weighted
//   Kogge-Stone scan (shfl_up, weights a^(16d)); running register U makes
//   the within-chain combine exact; chain-start halo = 256-step truncation
//   (a^256 ~ 1.5e-3, validated absmax floor 0.0039).
//   Raw v_log/v_exp/v_sqrt transcendentals; nontemporal float4 stores.
//   5120 waves (20/CU demand), no barriers -> free-running bus mix.
//
// M[t] = a*M[t-1] + s*x[t], M[0]=x[0]
// out  = sqrt(x*(M+eps)^-0.98 + 2) - sqrt(2)

#define B_      64
#define T_      8192
#define F4_     20                // 80 f32 = 20 float4
#define NSEQ4   (B_ * F4_)        // 1280 float4 lanes
#define LCH_    16                // steps per chunk
#define CPW_    16                // chunks per wave
#define SQW_    4                 // seq4 per wave
#define SPAN_   (CPW_ * LCH_)     // 256 steps
#define SPC_    2                 // produce spans per chain
#define CHAIN_  (SPC_ * SPAN_)    // 512 steps
#define TSPLIT_ (T_ / CHAIN_)     // 16 chains per seq
#define WPB_    4                 // waves per block (independent)
#define SEQB_   (SQW_ * WPB_)     // 16 seq4 per block
#define NG_     (NSEQ4 / SEQB_)   // 80 -> grid 1280, 5120 waves
#define SA_     0.025f
#define AA_     0.975f
#define A8_     0.81665182f       // a^8
#define A16_1   0.66692016f       // a^16
#define A16_2   0.44478250f       // a^32
#define A16_4   0.19783147f       // a^64
#define A16_8   0.039137292f      // a^128
#define A16_16  0.0015317278f     // a^256
#define L2A16_  -0.58441544f      // log2(a^16)
#define A16S_   26.676807f        // a^16/s (chunk-0 exact fix, u-space)

typedef float f4v __attribute__((ext_vector_type(4)));

__device__ __forceinline__ float pcen1(float xv, float m) {
    float l = __builtin_amdgcn_logf(m + 1e-6f);        // v_log_f32 (log2)
    float g = __builtin_amdgcn_exp2f(-0.98f * l);      // (m+eps)^(-alpha)
    return __builtin_amdgcn_sqrtf(fmaf(xv, g, 2.0f)) - 1.4142135623730951f;
}

__device__ __forceinline__ f4v pcen4(float4 xv, float4 m) {
    f4v o;
    o.x = pcen1(xv.x, m.x);
    o.y = pcen1(xv.y, m.y);
    o.z = pcen1(xv.z, m.z);
    o.w = pcen1(xv.w, m.w);
    return o;
}

// d = c*d + v
__device__ __forceinline__ void hstep(float4& d, float c, const float4 v) {
    d.x = fmaf(c, d.x, v.x);
    d.y = fmaf(c, d.y, v.y);
    d.z = fmaf(c, d.z, v.z);
    d.w = fmaf(c, d.w, v.w);
}

// d += c*v
__device__ __forceinline__ void faxpy(float4& d, float c, const float4 v) {
    d.x = fmaf(c, v.x, d.x);
    d.y = fmaf(c, v.y, d.y);
    d.z = fmaf(c, v.z, d.z);
    d.w = fmaf(c, v.w, d.w);
}

// m = a*m + s*x
__device__ __forceinline__ void ema4(float4& m, const float4 xv) {
    m.x = fmaf(AA_, m.x, SA_ * xv.x);
    m.y = fmaf(AA_, m.y, SA_ * xv.y);
    m.z = fmaf(AA_, m.z, SA_ * xv.z);
    m.w = fmaf(AA_, m.w, SA_ * xv.w);
}

__device__ __forceinline__ float4 shfl_up4(float4 v, int d) {
    float4 r;
    r.x = __shfl_up(v.x, d, 64);
    r.y = __shfl_up(v.y, d, 64);
    r.z = __shfl_up(v.z, d, 64);
    r.w = __shfl_up(v.w, d, 64);
    return r;
}

__device__ __forceinline__ float4 bcast4(float4 v, int srcLane) {
    float4 r;
    r.x = __shfl(v.x, srcLane, 64);
    r.y = __shfl(v.y, srcLane, 64);
    r.z = __shfl(v.z, srcLane, 64);
    r.w = __shfl(v.w, srcLane, 64);
    return r;
}

// u-space zero-init partial over 16 steps (two independent 8-chains)
__device__ __forceinline__ float4 partial16(const float4 (&xv)[LCH_]) {
    float4 u0 = make_float4(0.f, 0.f, 0.f, 0.f);
    float4 u1 = make_float4(0.f, 0.f, 0.f, 0.f);
    #pragma unroll
    for (int j = 0; j < 8; ++j) {
        hstep(u0, AA_, xv[j]);
        hstep(u1, AA_, xv[j + 8]);
    }
    float4 pu = u1;
    faxpy(pu, A8_, u0);                    // pu = a^8*u0 + u1
    return pu;
}

// inclusive weighted scan over 16 chunk-lanes: v(lc) = sum A16^(lc-k) P(k)
__device__ __forceinline__ float4 scan16(float4 v, int lc) {
    float4 t;
    t = shfl_up4(v, 4);  faxpy(v, (lc >= 1) ? A16_1 : 0.f, t);
    t = shfl_up4(v, 8);  faxpy(v, (lc >= 2) ? A16_2 : 0.f, t);
    t = shfl_up4(v, 16); faxpy(v, (lc >= 4) ? A16_4 : 0.f, t);
    t = shfl_up4(v, 32); faxpy(v, (lc >= 8) ? A16_8 : 0.f, t);
    return v;
}

__global__ void __launch_bounds__(256, 4)
pcen_wavescan(const float4* __restrict__ x4, float4* __restrict__ o4) {
    const int tid  = threadIdx.x;
    const int wv   = tid >> 6;
    const int lane = tid & 63;
    const int s    = lane & (SQW_ - 1);    // seq4 within wave
    const int lc   = lane >> 2;            // chunk 0..15

    const int g     = blockIdx.x % NG_;
    const int chain = blockIdx.x / NG_;

    const int r  = g * SEQB_ + wv * SQW_ + s;
    const int b  = r / F4_;
    const int f4 = r - b * F4_;

    const size_t seqbase = (size_t)b * ((size_t)T_ * F4_) + f4;
    const int    tch     = chain * CHAIN_ + lc * LCH_;   // own chunk, span 0
    const float4* xp = x4 + seqbase + (size_t)tch * F4_;
    float4*       op = o4 + seqbase + (size_t)tch * F4_;

    const float powAlc = __builtin_amdgcn_exp2f((float)lc * L2A16_);  // a^(16*lc)
    const int   bsrc   = 60 + s;           // lane holding v(15) for this s

    float4 U = make_float4(0.f, 0.f, 0.f, 0.f);
    float4 xv[LCH_];

    // ---- halo span: 256-step truncated carry init (chain>0, block-uniform)
    if (chain > 0) {
        const float4* hp = xp - (size_t)SPAN_ * F4_;
        #pragma unroll
        for (int j = 0; j < LCH_; ++j) xv[j] = hp[(size_t)j * F4_];
        float4 v = scan16(partial16(xv), lc);
        U = bcast4(v, bsrc);               // U = v(15) = halo-span total
    }

    const size_t so = (size_t)SPAN_ * F4_;

    #pragma unroll
    for (int sp = 0; sp < SPC_; ++sp) {
        const float4* xs = xp + (size_t)sp * so;
        float4*       os = op + (size_t)sp * so;

        #pragma unroll
        for (int j = 0; j < LCH_; ++j) xv[j] = xs[(size_t)j * F4_];

        const bool c0 = (chain == 0 && sp == 0 && lc == 0);

        float4 pu = partial16(xv);
        faxpy(pu, c0 ? A16S_ : 0.f, xv[0]);    // exact M[0]=x[0] fix (u-space)

        float4 v = scan16(pu, lc);

        // carry into own chunk: u = a^(16*lc)*U + v(lc-1)
        float4 vp = shfl_up4(v, 4);
        const float pm = (lc == 0) ? 0.f : 1.f;
        float4 u;
        u.x = fmaf(powAlc, U.x, pm * vp.x);
        u.y = fmaf(powAlc, U.y, pm * vp.y);
        u.z = fmaf(powAlc, U.z, pm * vp.z);
        u.w = fmaf(powAlc, U.w, pm * vp.w);

        // advance running carry (exact within chain): U = a^256*U + v(15)
        float4 S = bcast4(v, bsrc);
        U.x = fmaf(A16_16, U.x, S.x);
        U.y = fmaf(A16_16, U.y, S.y);
        U.z = fmaf(A16_16, U.z, S.z);
        U.w = fmaf(A16_16, U.w, S.w);

        // produce: m = s*u, then 16 EMA + pcen steps, NT stores
        float4 m;
        m.x = SA_ * u.x; m.y = SA_ * u.y; m.z = SA_ * u.z; m.w = SA_ * u.w;

        ema4(m, xv[0]);
        faxpy(m, c0 ? AA_ : 0.f, xv[0]);       // global t=0: m = x[0] exactly
        __builtin_nontemporal_store(pcen4(xv[0], m), (f4v*)os);
        #pragma unroll
        for (int j = 1; j < LCH_; ++j) {
            ema4(m, xv[j]);
            __builtin_nontemporal_store(pcen4(xv[j], m),
                                        (f4v*)(os + (size_t)j * F4_));
        }
    }
}

extern "C" void kernel_launch(void* const* d_in, const int* in_sizes, int n_in,
                              void* d_out, int out_size, void* d_ws, size_t ws_size,
                              hipStream_t stream) {
    const float4* x4 = (const float4*)d_in[0];
    float4*       o4 = (float4*)d_out;

    pcen_wavescan<<<dim3(NG_ * TSPLIT_), dim3(256), 0, stream>>>(x4, o4);
}